// Round 6
// baseline (11508.746 us; speedup 1.0000x reference)
//
#include <hip/hip_runtime.h>
#include <hip/hip_bf16.h>
#include <cstddef>

#define kT 256
#define kB 128
#define kINP 512
#define kH 512
#define kK 32
#define kR 64
#define kNEG (-1e30f)

// ---------------------------------------------------------------------------
// agent-scope (device-coherent, cache-bypassing) accessors, RELAXED order.
// Cross-pair ordering: set_flag's __syncthreads drains vmcnt before the flag
// store; spinners read data only after seeing the flag (validated r3-r5).
// ---------------------------------------------------------------------------
__device__ __forceinline__ void ag_store(float* p, float v) {
    __hip_atomic_store(p, v, __ATOMIC_RELAXED, __HIP_MEMORY_SCOPE_AGENT);
}
__device__ __forceinline__ float ag_load(const float* p) {
    return __hip_atomic_load(p, __ATOMIC_RELAXED, __HIP_MEMORY_SCOPE_AGENT);
}

// fast tanh for attention scores (error ~1e-7, stable at +-inf)
__device__ __forceinline__ float ftanh(float x)
{
    float e = __expf(2.0f * x);
    return 1.0f - 2.0f * __builtin_amdgcn_rcpf(e + 1.0f);
}

// ---------------------------------------------------------------------------
// XU = x @ Uw + Ub.  64x64 tile, BK=32, 256 threads, 4x4 acc/thread.
// ---------------------------------------------------------------------------
__global__ __launch_bounds__(256) void gemm_xu(
    const float* __restrict__ A, const float* __restrict__ W,
    const float* __restrict__ bias, float* __restrict__ C)
{
    __shared__ float At[32][68];   // A tile transposed: At[k][m]
    __shared__ float Ws[32][68];
    const int tid = threadIdx.x;
    const int n0 = blockIdx.x * 64;
    const int m0 = blockIdx.y * 64;
    const int tx = tid & 15, ty = tid >> 4;
    const int arow = tid >> 3, ak = (tid & 7) << 2;
    const int wrow = tid >> 4, wc = (tid & 15) << 2;

    float acc[4][4] = {};

    for (int k0 = 0; k0 < kINP; k0 += 32) {
        float4 a0 = *reinterpret_cast<const float4*>(&A[(size_t)(m0 + arow) * kINP + k0 + ak]);
        float4 a1 = *reinterpret_cast<const float4*>(&A[(size_t)(m0 + 32 + arow) * kINP + k0 + ak]);
        float4 w0 = *reinterpret_cast<const float4*>(&W[(size_t)(k0 + wrow) * kH + n0 + wc]);
        float4 w1 = *reinterpret_cast<const float4*>(&W[(size_t)(k0 + wrow + 16) * kH + n0 + wc]);
        __syncthreads();
        At[ak + 0][arow] = a0.x; At[ak + 1][arow] = a0.y;
        At[ak + 2][arow] = a0.z; At[ak + 3][arow] = a0.w;
        At[ak + 0][32 + arow] = a1.x; At[ak + 1][32 + arow] = a1.y;
        At[ak + 2][32 + arow] = a1.z; At[ak + 3][32 + arow] = a1.w;
        *reinterpret_cast<float4*>(&Ws[wrow][wc]) = w0;
        *reinterpret_cast<float4*>(&Ws[wrow + 16][wc]) = w1;
        __syncthreads();
#pragma unroll
        for (int kk = 0; kk < 32; ++kk) {
            float4 a4 = *reinterpret_cast<float4*>(&At[kk][ty * 4]);
            float4 w4 = *reinterpret_cast<float4*>(&Ws[kk][tx * 4]);
            float a_[4] = {a4.x, a4.y, a4.z, a4.w};
            float w_[4] = {w4.x, w4.y, w4.z, w4.w};
#pragma unroll
            for (int r = 0; r < 4; ++r)
#pragma unroll
                for (int c = 0; c < 4; ++c)
                    acc[r][c] += a_[r] * w_[c];
        }
    }

#pragma unroll
    for (int r = 0; r < 4; ++r) {
        int m = m0 + ty * 4 + r;
#pragma unroll
        for (int c = 0; c < 4; ++c) {
            int n = n0 + tx * 4 + c;
            C[(size_t)m * kH + n] = acc[r][c] + bias[n];
        }
    }
}

__global__ __launch_bounds__(256) void init_flags_k(int* __restrict__ flags)
{
    int i = blockIdx.x * 256 + threadIdx.x;
    if (i < kB * 3 * 2) flags[i] = 0;
}

// ---------------------------------------------------------------------------
// Pair-split persistent recurrence: blockIdx = 2*b + half, 1024 threads.
// shortH/shortU (last-32 h / u rows, own 256-col half) in LDS; longH/longU
// in block-private global (L2-resident). va-matvec fused into the pre-wait
// A-phase; per-wave register softmax; 11 barriers + 3 relaxed spins/step.
// ---------------------------------------------------------------------------
__global__ __launch_bounds__(1024) void rnn_pair(
    const float* __restrict__ Vw, const float* __restrict__ Vaw,
    const float* __restrict__ Uaw, const float* __restrict__ vvec,
    const float* __restrict__ XU, float* __restrict__ lngU,
    float* __restrict__ lngH, float* __restrict__ hs,
    float* __restrict__ esx, float* __restrict__ stx, int* __restrict__ flags)
{
    extern __shared__ float dyn[];
    float* shortH = dyn;               // [32][256]
    float* shortU = dyn + 32 * 256;    // [32][256]
    float* part   = dyn + 64 * 256;    // [16][260]
    float* part2  = part + 16 * 260;   // [16][260]
    const int PSTR = 260;

    const int bid = blockIdx.x;
    const int b = bid >> 1, half = bid & 1;
    const int C0 = half << 8;            // own column base
    const int P0 = (half ^ 1) << 8;      // partner column base
    const int tid = threadIdx.x;
    const int kq = tid >> 6;             // wave id 0..15 (k-split group)
    const int lane = tid & 63;
    const int c4 = lane << 2;            // float4 col offset within half

    __shared__ __align__(16) float h_sh[512];     // full h_{t-1}
    __shared__ __align__(16) float st_sh[512];    // full st
    __shared__ __align__(16) float va_sh[256];    // own cols of va
    __shared__ __align__(16) float v_sh[256];     // own cols of v
    __shared__ float es_own[96], es_sh[96];
    __shared__ int   rowm[96];
    __shared__ float lsc_sh[kT];
    __shared__ float buck_sh[kR];
    __shared__ int   lidx_sh[kR];
    __shared__ int   fcnt_sh, evict_pos;

    float* lngU_b = lngU + (size_t)bid * kR * 256;
    float* lngH_b = lngH + (size_t)bid * kR * 256;

    int* fC_own = &flags[(b * 3 + 0) * 2 + half];
    int* fB_own = &flags[(b * 3 + 1) * 2 + half];
    int* fS_own = &flags[(b * 3 + 2) * 2 + half];
    int* fC_par = &flags[(b * 3 + 0) * 2 + (half ^ 1)];
    int* fB_par = &flags[(b * 3 + 1) * 2 + (half ^ 1)];
    int* fS_par = &flags[(b * 3 + 2) * 2 + (half ^ 1)];

    // all threads spin (relaxed, same address coalesces to 1 fetch/wave)
    auto spin_ge = [&](int* f, int target) {
        while (__hip_atomic_load(f, __ATOMIC_RELAXED, __HIP_MEMORY_SCOPE_AGENT) < target)
            __builtin_amdgcn_s_sleep(2);
    };
    auto set_flag = [&](int* f, int val) {
        __syncthreads();   // drains vmcnt(0): prior agent stores at coherence point
        if (tid == 0)
            __hip_atomic_store(f, val, __ATOMIC_RELAXED, __HIP_MEMORY_SCOPE_AGENT);
    };

    // ---- prologue (t = 0): st_0 = pre = XU[0][b];  h_0 = tanh(pre)
    if (tid < 256) { v_sh[tid] = vvec[C0 + tid]; lsc_sh[tid] = 0.0f; }
    if (tid < kR) { buck_sh[tid] = 0.0f; lidx_sh[tid] = -1; }
    if (tid == 0) fcnt_sh = 0;
    if (tid < 512) st_sh[tid] = XU[(size_t)b * kH + tid];
    __syncthreads();
    if (tid < 256) {
        float h0 = tanhf(st_sh[C0 + tid]);
        h_sh[C0 + tid] = h0;
        shortH[tid] = h0;                       // slot 0 <- h_0
        ag_store(&hs[(size_t)b * kH + C0 + tid], h0);
    }
    set_flag(fC_own, 1);

    for (int t = 1; t < kT; ++t) {
        float xu_reg = (tid < 256) ? XU[((size_t)t * kB + b) * kH + C0 + tid] : 0.0f;

        // ---- A1 (pre-wait): va partials = st_{t-1} @ Vaw[:, C], full k
        float4 av4 = {0, 0, 0, 0};
#pragma unroll 8
        for (int k = kq; k < kH; k += 16) {
            float s = st_sh[k];
            const float4 w = *reinterpret_cast<const float4*>(&Vaw[(size_t)k * kH + C0 + c4]);
            av4.x += s * w.x; av4.y += s * w.y; av4.z += s * w.z; av4.w += s * w.w;
        }
        // ---- A2 (pre-wait): u partials, own-k half
        float4 au4 = {0, 0, 0, 0};
#pragma unroll 8
        for (int k = C0 + kq; k < C0 + 256; k += 16) {
            float s = h_sh[k];
            const float4 w = *reinterpret_cast<const float4*>(&Uaw[(size_t)k * kH + C0 + c4]);
            au4.x += s * w.x; au4.y += s * w.y; au4.z += s * w.z; au4.w += s * w.w;
        }
        if (tid < 96) {
            int row;
            if (tid < kK) { int md = (t + 31 - tid) & 31; row = t - 1 - md; }
            else row = lidx_sh[tid - kK];
            rowm[tid] = row;
        }
        // ---- partner h_{t-1} half
        spin_ge(fC_par, t);
        if (tid < 256) h_sh[P0 + tid] = ag_load(&hs[((size_t)(t - 1) * kB + b) * kH + P0 + tid]);
        __syncthreads();                                              // B1
        // ---- A3: u partials, partner-k half
#pragma unroll 8
        for (int k = P0 + kq; k < P0 + 256; k += 16) {
            float s = h_sh[k];
            const float4 w = *reinterpret_cast<const float4*>(&Uaw[(size_t)k * kH + C0 + c4]);
            au4.x += s * w.x; au4.y += s * w.y; au4.z += s * w.z; au4.w += s * w.w;
        }
        *reinterpret_cast<float4*>(&part[kq * PSTR + c4]) = au4;
        *reinterpret_cast<float4*>(&part2[kq * PSTR + c4]) = av4;
        __syncthreads();                                              // B2
        if (tid < 256) {
            float u = 0.0f, va = 0.0f;
#pragma unroll
            for (int j = 0; j < 16; ++j) { u += part[j * PSTR + tid]; va += part2[j * PSTR + tid]; }
            shortU[((t - 1) & 31) * 256 + tid] = u;    // slot (t-1)%32 <- u_{t-1}
            va_sh[tid] = va;
        }
        __syncthreads();                                              // B3

        // ---- es partials over own cols: wave kq -> rows m = kq + 16r
        {
            float4 uu[6]; int rv[6];
            const float4 vav = *reinterpret_cast<const float4*>(&va_sh[c4]);
            const float4 vvv = *reinterpret_cast<const float4*>(&v_sh[c4]);
#pragma unroll
            for (int r = 0; r < 6; ++r) {
                int m = kq + (r << 4);
                int row = rowm[m]; rv[r] = row;
                uu[r] = make_float4(0.f, 0.f, 0.f, 0.f);
                if (row >= 0) {
                    const float* up = (m < kK) ? &shortU[m * 256]
                                               : &lngU_b[(size_t)(m - kK) * 256];
                    uu[r] = *reinterpret_cast<const float4*>(&up[c4]);
                }
            }
#pragma unroll
            for (int r = 0; r < 6; ++r) {
                float p = 0.0f;
                if (rv[r] >= 0) {
                    p = vvv.x * ftanh(vav.x + uu[r].x) + vvv.y * ftanh(vav.y + uu[r].y)
                      + vvv.z * ftanh(vav.z + uu[r].z) + vvv.w * ftanh(vav.w + uu[r].w);
                }
#pragma unroll
                for (int off = 32; off; off >>= 1) p += __shfl_down(p, off);
                if (lane == 0) {
                    int m = kq + (r << 4);
                    es_own[m] = p;
                    ag_store(&esx[((size_t)b * 2 + half) * 96 + m], p);
                }
            }
        }
        set_flag(fB_own, t);                                          // B4 + flag
        spin_ge(fB_par, t);
        if (tid < 96) {
            float e = kNEG;
            if (rowm[tid] >= 0)
                e = es_own[tid] + ag_load(&esx[((size_t)b * 2 + (half ^ 1)) * 96 + tid]);
            es_sh[tid] = e;
        }
        __syncthreads();                                              // B5

        // ---- per-wave register softmax over 96 (redundant, no barriers)
        float mx, inv;
        {
            float a = es_sh[lane];
            float b2 = (lane < 32) ? es_sh[64 + lane] : kNEG;
            float m2 = fmaxf(a, b2);
#pragma unroll
            for (int off = 32; off; off >>= 1) m2 = fmaxf(m2, __shfl_xor(m2, off));
            mx = m2;
            float e = __expf(a - mx) + ((lane < 32) ? __expf(b2 - mx) : 0.0f);
#pragma unroll
            for (int off = 32; off; off >>= 1) e += __shfl_xor(e, off);
            inv = 1.0f / e;
        }

        // ---- ct partials over own cols (shortH LDS, longH global/L2)
        {
            float4 hv[6]; float wq[6];
#pragma unroll
            for (int r = 0; r < 6; ++r) {
                int m = kq + (r << 4);
                int row = rowm[m];
                hv[r] = make_float4(0.f, 0.f, 0.f, 0.f); wq[r] = 0.0f;
                if (row >= 0) {
                    const float* hp = (m < kK) ? &shortH[m * 256]
                                               : &lngH_b[(size_t)(m - kK) * 256];
                    hv[r] = *reinterpret_cast<const float4*>(&hp[c4]);
                    wq[r] = __expf(es_sh[m] - mx);
                }
            }
            float4 acc = {0, 0, 0, 0};
#pragma unroll
            for (int r = 0; r < 6; ++r) {
                acc.x += wq[r] * hv[r].x; acc.y += wq[r] * hv[r].y;
                acc.z += wq[r] * hv[r].z; acc.w += wq[r] * hv[r].w;
            }
            *reinterpret_cast<float4*>(&part[kq * PSTR + c4]) = acc;
        }
        __syncthreads();                                              // B6
        if (tid < 256) {
            float ct = 0.0f;
#pragma unroll
            for (int j = 0; j < 16; ++j) ct += part[j * PSTR + tid];
            float stv = 0.5f * (h_sh[C0 + tid] + ct * inv);
            st_sh[C0 + tid] = stv;
            ag_store(&stx[(size_t)b * kH + C0 + tid], stv);
        }
        set_flag(fS_own, t);                                          // B7 + flag

        // ---- long_scores accumulate + eviction decision (wave 0 only;
        //      same-wave LDS ordering, no barrier needed inside)
        if (tid < kK) {
            int row = rowm[tid];
            if (row >= 0) lsc_sh[row] += __expf(es_sh[tid] - mx) * inv;
        }
        if (tid == 0) {
            int ep = -1;
            if (t >= kK) {
                float score = lsc_sh[t - kK];
                int fc = fcnt_sh;
                bool nf = fc < kR;
                float mn = buck_sh[0]; int mp = 0;
                for (int r = 1; r < kR; ++r) {
                    float bv = buck_sh[r];
                    if (bv < mn) { mn = bv; mp = r; }
                }
                if (nf || score > mn) {
                    ep = nf ? fc : mp;
                    lidx_sh[ep] = t - kK;
                    buck_sh[ep] = score;
                    if (nf) fcnt_sh = fc + 1;
                }
            }
            evict_pos = ep;
        }
        __syncthreads();                                              // B8
        // evicted candidate = h_{t-32} / u_{t-32} in slot t%32 (copy before
        // the slot is overwritten with h_t below)
        if (evict_pos >= 0 && tid < 256) {
            lngH_b[(size_t)evict_pos * 256 + tid] = shortH[(t & 31) * 256 + tid];
            lngU_b[(size_t)evict_pos * 256 + tid] = shortU[(t & 31) * 256 + tid];
        }

        // ---- matvec B: h_pre = st @ Vw[:, C] + XU[t]  (own-k, then partner)
        float4 aw4 = {0, 0, 0, 0};
#pragma unroll 8
        for (int k = C0 + kq; k < C0 + 256; k += 16) {
            float s = st_sh[k];
            const float4 w = *reinterpret_cast<const float4*>(&Vw[(size_t)k * kH + C0 + c4]);
            aw4.x += s * w.x; aw4.y += s * w.y; aw4.z += s * w.z; aw4.w += s * w.w;
        }
        spin_ge(fS_par, t);
        if (tid < 256) st_sh[P0 + tid] = ag_load(&stx[(size_t)b * kH + P0 + tid]);
        __syncthreads();                                              // B9
#pragma unroll 8
        for (int k = P0 + kq; k < P0 + 256; k += 16) {
            float s = st_sh[k];
            const float4 w = *reinterpret_cast<const float4*>(&Vw[(size_t)k * kH + C0 + c4]);
            aw4.x += s * w.x; aw4.y += s * w.y; aw4.z += s * w.z; aw4.w += s * w.w;
        }
        *reinterpret_cast<float4*>(&part[kq * PSTR + c4]) = aw4;
        __syncthreads();                                              // B10
        if (tid < 256) {
            float hpre = xu_reg;
#pragma unroll
            for (int j = 0; j < 16; ++j) hpre += part[j * PSTR + tid];
            float hval = tanhf(hpre);
            h_sh[C0 + tid] = hval;
            shortH[(t & 31) * 256 + tid] = hval;       // slot t%32 <- h_t
            ag_store(&hs[((size_t)t * kB + b) * kH + C0 + tid], hval);
        }
        set_flag(fC_own, t + 1);                                      // B11 + flag
    }
}

// ---------------------------------------------------------------------------
extern "C" void kernel_launch(void* const* d_in, const int* in_sizes, int n_in,
                              void* d_out, int out_size, void* d_ws, size_t ws_size,
                              hipStream_t stream)
{
    const float* x   = (const float*)d_in[0];
    const float* Uw  = (const float*)d_in[1];
    const float* Ub  = (const float*)d_in[2];
    const float* Vw  = (const float*)d_in[3];
    const float* Uaw = (const float*)d_in[4];
    const float* Vaw = (const float*)d_in[5];
    const float* vv  = (const float*)d_in[6];
    float* hs = (float*)d_out;

    float* ws = (float*)d_ws;
    const size_t TBH = (size_t)kT * kB * kH;
    float* XU   = ws;                              // T*B*H
    float* lngU = XU + TBH;                        // 2B * 64 * 256
    float* lngH = lngU + (size_t)2 * kB * kR * 256;
    float* esx  = lngH + (size_t)2 * kB * kR * 256;
    float* stx  = esx + (size_t)kB * 2 * 96;       // B*H
    int*   flags = (int*)(stx + (size_t)kB * kH);  // B*3*2

    // dynamic LDS: shortH(32K) + shortU(32K) + part(16.6K) + part2(16.6K)
    const int dyn_bytes = (64 * 256 + 2 * 16 * 260) * 4;
    hipFuncSetAttribute(reinterpret_cast<const void*>(rnn_pair),
                        hipFuncAttributeMaxDynamicSharedMemorySize, dyn_bytes);

    init_flags_k<<<3, 256, 0, stream>>>(flags);

    // XU = x @ Uw + Ub
    gemm_xu<<<dim3(kH / 64, (kT * kB) / 64), 256, 0, stream>>>(x, Uw, Ub, XU);

    // pair-split recurrence: 2 blocks per batch element, 1024 threads each
    rnn_pair<<<2 * kB, 1024, dyn_bytes, stream>>>(
        Vw, Vaw, Uaw, vv, XU, lngU, lngH, hs, esx, stx, flags);
}

// Round 7
// 9034.055 us; speedup vs baseline: 1.2739x; 1.2739x over previous
//
#include <hip/hip_runtime.h>
#include <hip/hip_bf16.h>
#include <cstddef>

#define kT 256
#define kB 128
#define kINP 512
#define kH 512
#define kK 32
#define kR 64
#define kNEG (-1e30f)

// ---------------------------------------------------------------------------
// agent-scope (device-coherent, cache-bypassing) accessors, RELAXED order.
// Cross-pair ordering: set_flag's __syncthreads drains vmcnt before the flag
// store; spinners read data only after seeing the flag (validated r3-r6).
// ---------------------------------------------------------------------------
__device__ __forceinline__ void ag_store(float* p, float v) {
    __hip_atomic_store(p, v, __ATOMIC_RELAXED, __HIP_MEMORY_SCOPE_AGENT);
}
__device__ __forceinline__ float ag_load(const float* p) {
    return __hip_atomic_load(p, __ATOMIC_RELAXED, __HIP_MEMORY_SCOPE_AGENT);
}

// fast tanh for attention scores (error ~1e-7, stable at +-inf)
__device__ __forceinline__ float ftanh(float x)
{
    float e = __expf(2.0f * x);
    return 1.0f - 2.0f * __builtin_amdgcn_rcpf(e + 1.0f);
}

// ---------------------------------------------------------------------------
// XU = x @ Uw + Ub.  64x64 tile, BK=32, 256 threads, 4x4 acc/thread.
// ---------------------------------------------------------------------------
__global__ __launch_bounds__(256) void gemm_xu(
    const float* __restrict__ A, const float* __restrict__ W,
    const float* __restrict__ bias, float* __restrict__ C)
{
    __shared__ float At[32][68];   // A tile transposed: At[k][m]
    __shared__ float Ws[32][68];
    const int tid = threadIdx.x;
    const int n0 = blockIdx.x * 64;
    const int m0 = blockIdx.y * 64;
    const int tx = tid & 15, ty = tid >> 4;
    const int arow = tid >> 3, ak = (tid & 7) << 2;
    const int wrow = tid >> 4, wc = (tid & 15) << 2;

    float acc[4][4] = {};

    for (int k0 = 0; k0 < kINP; k0 += 32) {
        float4 a0 = *reinterpret_cast<const float4*>(&A[(size_t)(m0 + arow) * kINP + k0 + ak]);
        float4 a1 = *reinterpret_cast<const float4*>(&A[(size_t)(m0 + 32 + arow) * kINP + k0 + ak]);
        float4 w0 = *reinterpret_cast<const float4*>(&W[(size_t)(k0 + wrow) * kH + n0 + wc]);
        float4 w1 = *reinterpret_cast<const float4*>(&W[(size_t)(k0 + wrow + 16) * kH + n0 + wc]);
        __syncthreads();
        At[ak + 0][arow] = a0.x; At[ak + 1][arow] = a0.y;
        At[ak + 2][arow] = a0.z; At[ak + 3][arow] = a0.w;
        At[ak + 0][32 + arow] = a1.x; At[ak + 1][32 + arow] = a1.y;
        At[ak + 2][32 + arow] = a1.z; At[ak + 3][32 + arow] = a1.w;
        *reinterpret_cast<float4*>(&Ws[wrow][wc]) = w0;
        *reinterpret_cast<float4*>(&Ws[wrow + 16][wc]) = w1;
        __syncthreads();
#pragma unroll
        for (int kk = 0; kk < 32; ++kk) {
            float4 a4 = *reinterpret_cast<float4*>(&At[kk][ty * 4]);
            float4 w4 = *reinterpret_cast<float4*>(&Ws[kk][tx * 4]);
            float a_[4] = {a4.x, a4.y, a4.z, a4.w};
            float w_[4] = {w4.x, w4.y, w4.z, w4.w};
#pragma unroll
            for (int r = 0; r < 4; ++r)
#pragma unroll
                for (int c = 0; c < 4; ++c)
                    acc[r][c] += a_[r] * w_[c];
        }
    }

#pragma unroll
    for (int r = 0; r < 4; ++r) {
        int m = m0 + ty * 4 + r;
#pragma unroll
        for (int c = 0; c < 4; ++c) {
            int n = n0 + tx * 4 + c;
            C[(size_t)m * kH + n] = acc[r][c] + bias[n];
        }
    }
}

__global__ __launch_bounds__(256) void init_flags_k(int* __restrict__ flags)
{
    int i = blockIdx.x * 256 + threadIdx.x;
    if (i < kB * 3 * 2) flags[i] = 0;
}

// ---------------------------------------------------------------------------
// Pair-split persistent recurrence, 1024 threads/block.
// XCD-half co-location: bid = (b%4) + 4*half + 8*(b/4), so under round-robin
// dispatch XCDs 0-3 host only half-0 blocks, XCDs 4-7 only half-1. Per-XCD
// L2 footprint = 1.5 MB weight halves + 2 MB lngU < 4 MB (fits).
// On-chip caches (own 256-col half): shortH/shortU (last-32 h/u) + longH
// (64 long-term h rows) in LDS; lngU in block-private global (L2-resident).
// A-phase wave split: waves 8-15 full-k va partials (pre-wait), waves 0-7
// u partials own-k pre-wait / partner-k post-wait. Per-wave register softmax.
// ---------------------------------------------------------------------------
__global__ __launch_bounds__(1024) void rnn_pair(
    const float* __restrict__ Vw, const float* __restrict__ Vaw,
    const float* __restrict__ Uaw, const float* __restrict__ vvec,
    const float* __restrict__ XU, float* __restrict__ lngU,
    float* __restrict__ hs, float* __restrict__ esx,
    float* __restrict__ stx, int* __restrict__ flags)
{
    extern __shared__ float dyn[];
    float* shortH = dyn;               // [32][256]
    float* shortU = dyn + 32 * 256;    // [32][256]
    float* longH  = dyn + 64 * 256;    // [64][256]
    float* part   = dyn + 128 * 256;   // [16][260]
    const int PSTR = 260;

    const int bid = blockIdx.x;
    const int half = (bid >> 2) & 1;
    const int b = (bid & 3) | ((bid >> 3) << 2);
    const int C0 = half << 8;            // own column base
    const int P0 = (half ^ 1) << 8;      // partner column base
    const int tid = threadIdx.x;
    const int kq = tid >> 6;             // wave id 0..15
    const int kq8 = kq & 7;              // k-split id within 8-wave group
    const int lane = tid & 63;
    const int c4 = lane << 2;            // float4 col offset within half

    __shared__ __align__(16) float h_sh[512];     // full h_{t-1}
    __shared__ __align__(16) float st_sh[512];    // full st
    __shared__ __align__(16) float va_sh[256];    // own cols of va
    __shared__ __align__(16) float v_sh[256];     // own cols of v
    __shared__ float es_own[96], es_sh[96];
    __shared__ int   rowm[96];
    __shared__ float lsc_sh[kT];
    __shared__ float buck_sh[kR];
    __shared__ int   lidx_sh[kR];
    __shared__ int   fcnt_sh, evict_pos;

    float* lngU_b = lngU + (size_t)(b * 2 + half) * kR * 256;

    int* fC_own = &flags[(b * 3 + 0) * 2 + half];
    int* fB_own = &flags[(b * 3 + 1) * 2 + half];
    int* fS_own = &flags[(b * 3 + 2) * 2 + half];
    int* fC_par = &flags[(b * 3 + 0) * 2 + (half ^ 1)];
    int* fB_par = &flags[(b * 3 + 1) * 2 + (half ^ 1)];
    int* fS_par = &flags[(b * 3 + 2) * 2 + (half ^ 1)];

    auto spin_ge = [&](int* f, int target) {
        while (__hip_atomic_load(f, __ATOMIC_RELAXED, __HIP_MEMORY_SCOPE_AGENT) < target)
            __builtin_amdgcn_s_sleep(2);
    };
    auto set_flag = [&](int* f, int val) {
        __syncthreads();   // drains vmcnt(0): prior agent stores at coherence point
        if (tid == 0)
            __hip_atomic_store(f, val, __ATOMIC_RELAXED, __HIP_MEMORY_SCOPE_AGENT);
    };

    // ---- prologue (t = 0): st_0 = pre = XU[0][b];  h_0 = tanh(pre)
    if (tid < 256) { v_sh[tid] = vvec[C0 + tid]; lsc_sh[tid] = 0.0f; }
    if (tid < kR) { buck_sh[tid] = 0.0f; lidx_sh[tid] = -1; }
    if (tid == 0) fcnt_sh = 0;
    if (tid < 512) st_sh[tid] = XU[(size_t)b * kH + tid];
    __syncthreads();
    if (tid < 256) {
        float h0 = tanhf(st_sh[C0 + tid]);
        h_sh[C0 + tid] = h0;
        shortH[tid] = h0;                       // slot 0 <- h_0
        ag_store(&hs[(size_t)b * kH + C0 + tid], h0);
    }
    set_flag(fC_own, 1);

    for (int t = 1; t < kT; ++t) {
        float xu_reg = (tid < 256) ? XU[((size_t)t * kB + b) * kH + C0 + tid] : 0.0f;

        // ---- A-phase (pre-wait): waves 8-15 va = st_{t-1} @ Vaw[:,C] (full k);
        //      waves 0-7 u = h_{t-1} @ Uaw[:,C] own-k half
        float4 acc4 = {0, 0, 0, 0};
        if (kq >= 8) {
#pragma unroll 8
            for (int k = kq8; k < kH; k += 8) {
                float s = st_sh[k];
                const float4 w = *reinterpret_cast<const float4*>(&Vaw[(size_t)k * kH + C0 + c4]);
                acc4.x += s * w.x; acc4.y += s * w.y; acc4.z += s * w.z; acc4.w += s * w.w;
            }
        } else {
#pragma unroll 8
            for (int k = C0 + kq8; k < C0 + 256; k += 8) {
                float s = h_sh[k];
                const float4 w = *reinterpret_cast<const float4*>(&Uaw[(size_t)k * kH + C0 + c4]);
                acc4.x += s * w.x; acc4.y += s * w.y; acc4.z += s * w.z; acc4.w += s * w.w;
            }
        }
        if (tid < 96) {
            int row;
            if (tid < kK) { int md = (t + 31 - tid) & 31; row = t - 1 - md; }
            else row = lidx_sh[tid - kK];
            rowm[tid] = row;
        }
        // ---- partner h_{t-1} half
        spin_ge(fC_par, t);
        if (tid < 256) h_sh[P0 + tid] = ag_load(&hs[((size_t)(t - 1) * kB + b) * kH + P0 + tid]);
        __syncthreads();                                              // B1
        // ---- A-phase (post-wait): waves 0-7 u partner-k half
        if (kq < 8) {
#pragma unroll 8
            for (int k = P0 + kq8; k < P0 + 256; k += 8) {
                float s = h_sh[k];
                const float4 w = *reinterpret_cast<const float4*>(&Uaw[(size_t)k * kH + C0 + c4]);
                acc4.x += s * w.x; acc4.y += s * w.y; acc4.z += s * w.z; acc4.w += s * w.w;
            }
        }
        *reinterpret_cast<float4*>(&part[kq * PSTR + c4]) = acc4;
        __syncthreads();                                              // B2
        if (tid < 256) {
            float u = 0.0f, va = 0.0f;
#pragma unroll
            for (int j = 0; j < 8; ++j) {
                u += part[j * PSTR + tid];
                va += part[(j + 8) * PSTR + tid];
            }
            shortU[((t - 1) & 31) * 256 + tid] = u;    // slot (t-1)%32 <- u_{t-1}
            va_sh[tid] = va;
        }
        __syncthreads();                                              // B3

        // ---- es partials over own cols: wave kq -> rows m = kq + 16r
        {
            float4 uu[6]; int rv[6];
            const float4 vav = *reinterpret_cast<const float4*>(&va_sh[c4]);
            const float4 vvv = *reinterpret_cast<const float4*>(&v_sh[c4]);
#pragma unroll
            for (int r = 0; r < 6; ++r) {
                int m = kq + (r << 4);
                int row = rowm[m]; rv[r] = row;
                uu[r] = make_float4(0.f, 0.f, 0.f, 0.f);
                if (row >= 0) {
                    const float* up = (m < kK) ? &shortU[m * 256]
                                               : &lngU_b[(size_t)(m - kK) * 256];
                    uu[r] = *reinterpret_cast<const float4*>(&up[c4]);
                }
            }
#pragma unroll
            for (int r = 0; r < 6; ++r) {
                float p = 0.0f;
                if (rv[r] >= 0) {
                    p = vvv.x * ftanh(vav.x + uu[r].x) + vvv.y * ftanh(vav.y + uu[r].y)
                      + vvv.z * ftanh(vav.z + uu[r].z) + vvv.w * ftanh(vav.w + uu[r].w);
                }
#pragma unroll
                for (int off = 32; off; off >>= 1) p += __shfl_down(p, off);
                if (lane == 0) {
                    int m = kq + (r << 4);
                    es_own[m] = p;
                    ag_store(&esx[((size_t)b * 2 + half) * 96 + m], p);
                }
            }
        }
        set_flag(fB_own, t);                                          // B4 + flag
        spin_ge(fB_par, t);
        if (tid < 96) {
            float e = kNEG;
            if (rowm[tid] >= 0)
                e = es_own[tid] + ag_load(&esx[((size_t)b * 2 + (half ^ 1)) * 96 + tid]);
            es_sh[tid] = e;
        }
        __syncthreads();                                              // B5

        // ---- per-wave register softmax over 96 (redundant, no barriers)
        float mx, inv;
        {
            float a = es_sh[lane];
            float b2 = (lane < 32) ? es_sh[64 + lane] : kNEG;
            float m2 = fmaxf(a, b2);
#pragma unroll
            for (int off = 32; off; off >>= 1) m2 = fmaxf(m2, __shfl_xor(m2, off));
            mx = m2;
            float e = __expf(a - mx) + ((lane < 32) ? __expf(b2 - mx) : 0.0f);
#pragma unroll
            for (int off = 32; off; off >>= 1) e += __shfl_xor(e, off);
            inv = 1.0f / e;
        }

        // ---- ct partials over own cols (shortH / longH, both LDS)
        {
            float4 hv[6]; float wq[6];
#pragma unroll
            for (int r = 0; r < 6; ++r) {
                int m = kq + (r << 4);
                int row = rowm[m];
                hv[r] = make_float4(0.f, 0.f, 0.f, 0.f); wq[r] = 0.0f;
                if (row >= 0) {
                    const float* hp = (m < kK) ? &shortH[m * 256]
                                               : &longH[(m - kK) * 256];
                    hv[r] = *reinterpret_cast<const float4*>(&hp[c4]);
                    wq[r] = __expf(es_sh[m] - mx);
                }
            }
            float4 acc = {0, 0, 0, 0};
#pragma unroll
            for (int r = 0; r < 6; ++r) {
                acc.x += wq[r] * hv[r].x; acc.y += wq[r] * hv[r].y;
                acc.z += wq[r] * hv[r].z; acc.w += wq[r] * hv[r].w;
            }
            *reinterpret_cast<float4*>(&part[kq * PSTR + c4]) = acc;
        }
        __syncthreads();                                              // B6
        if (tid < 256) {
            float ct = 0.0f;
#pragma unroll
            for (int j = 0; j < 16; ++j) ct += part[j * PSTR + tid];
            float stv = 0.5f * (h_sh[C0 + tid] + ct * inv);
            st_sh[C0 + tid] = stv;
            ag_store(&stx[(size_t)b * kH + C0 + tid], stv);
        }
        set_flag(fS_own, t);                                          // B7 + flag

        // ---- long_scores accumulate + eviction decision (wave 0 only;
        //      same-wave LDS ordering, no barrier needed inside)
        if (tid < kK) {
            int row = rowm[tid];
            if (row >= 0) lsc_sh[row] += __expf(es_sh[tid] - mx) * inv;
        }
        if (tid == 0) {
            int ep = -1;
            if (t >= kK) {
                float score = lsc_sh[t - kK];
                int fc = fcnt_sh;
                bool nf = fc < kR;
                float mn = buck_sh[0]; int mp = 0;
                for (int r = 1; r < kR; ++r) {
                    float bv = buck_sh[r];
                    if (bv < mn) { mn = bv; mp = r; }
                }
                if (nf || score > mn) {
                    ep = nf ? fc : mp;
                    lidx_sh[ep] = t - kK;
                    buck_sh[ep] = score;
                    if (nf) fcnt_sh = fc + 1;
                }
            }
            evict_pos = ep;
        }
        __syncthreads();                                              // B8
        // evicted candidate = h_{t-32} / u_{t-32} in slot t%32 (copy before
        // the slot is overwritten with h_t below)
        if (evict_pos >= 0 && tid < 256) {
            longH[evict_pos * 256 + tid] = shortH[(t & 31) * 256 + tid];
            lngU_b[(size_t)evict_pos * 256 + tid] = shortU[(t & 31) * 256 + tid];
        }

        // ---- matvec B: h_pre = st @ Vw[:, C] + XU[t]  (own-k, then partner)
        float4 aw4 = {0, 0, 0, 0};
#pragma unroll 8
        for (int k = C0 + kq; k < C0 + 256; k += 16) {
            float s = st_sh[k];
            const float4 w = *reinterpret_cast<const float4*>(&Vw[(size_t)k * kH + C0 + c4]);
            aw4.x += s * w.x; aw4.y += s * w.y; aw4.z += s * w.z; aw4.w += s * w.w;
        }
        spin_ge(fS_par, t);
        if (tid < 256) st_sh[P0 + tid] = ag_load(&stx[(size_t)b * kH + P0 + tid]);
        __syncthreads();                                              // B9
#pragma unroll 8
        for (int k = P0 + kq; k < P0 + 256; k += 16) {
            float s = st_sh[k];
            const float4 w = *reinterpret_cast<const float4*>(&Vw[(size_t)k * kH + C0 + c4]);
            aw4.x += s * w.x; aw4.y += s * w.y; aw4.z += s * w.z; aw4.w += s * w.w;
        }
        *reinterpret_cast<float4*>(&part[kq * PSTR + c4]) = aw4;
        __syncthreads();                                              // B10
        if (tid < 256) {
            float hpre = xu_reg;
#pragma unroll
            for (int j = 0; j < 16; ++j) hpre += part[j * PSTR + tid];
            float hval = tanhf(hpre);
            h_sh[C0 + tid] = hval;
            shortH[(t & 31) * 256 + tid] = hval;       // slot t%32 <- h_t
            ag_store(&hs[((size_t)t * kB + b) * kH + C0 + tid], hval);
        }
        set_flag(fC_own, t + 1);                                      // B11 + flag
    }
}

// ---------------------------------------------------------------------------
extern "C" void kernel_launch(void* const* d_in, const int* in_sizes, int n_in,
                              void* d_out, int out_size, void* d_ws, size_t ws_size,
                              hipStream_t stream)
{
    const float* x   = (const float*)d_in[0];
    const float* Uw  = (const float*)d_in[1];
    const float* Ub  = (const float*)d_in[2];
    const float* Vw  = (const float*)d_in[3];
    const float* Uaw = (const float*)d_in[4];
    const float* Vaw = (const float*)d_in[5];
    const float* vv  = (const float*)d_in[6];
    float* hs = (float*)d_out;

    float* ws = (float*)d_ws;
    const size_t TBH = (size_t)kT * kB * kH;
    float* XU   = ws;                              // T*B*H
    float* lngU = XU + TBH;                        // 2B * 64 * 256
    float* esx  = lngU + (size_t)2 * kB * kR * 256;
    float* stx  = esx + (size_t)kB * 2 * 96;       // B*H
    int*   flags = (int*)(stx + (size_t)kB * kH);  // B*3*2

    // dynamic LDS: shortH(32K) + shortU(32K) + longH(64K) + part(16.6K)
    const int dyn_bytes = (32 * 256 + 32 * 256 + 64 * 256 + 16 * 260) * 4;
    hipFuncSetAttribute(reinterpret_cast<const void*>(rnn_pair),
                        hipFuncAttributeMaxDynamicSharedMemorySize, dyn_bytes);

    init_flags_k<<<3, 256, 0, stream>>>(flags);

    // XU = x @ Uw + Ub
    gemm_xu<<<dim3(kH / 64, (kT * kB) / 64), 256, 0, stream>>>(x, Uw, Ub, XU);

    // pair-split recurrence: 2 blocks per batch element, 1024 threads each
    rnn_pair<<<2 * kB, 1024, dyn_bytes, stream>>>(
        Vw, Vaw, Uaw, vv, XU, lngU, hs, esx, stx, flags);
}

// Round 9
// 6691.806 us; speedup vs baseline: 1.7198x; 1.3500x over previous
//
#include <hip/hip_runtime.h>
#include <hip/hip_bf16.h>
#include <cstddef>

#define kT 256
#define kB 128
#define kINP 512
#define kH 512
#define kK 32
#define kR 64
#define kNEG (-1e30f)

// ---------------------------------------------------------------------------
// agent-scope (device-coherent, cache-bypassing) accessors, RELAXED order.
// Cross-pair protocol (validated r3-r5): data via ag_store, then set_flag's
// __syncthreads drains each wave's vmcnt before tid0 stores the flag;
// partner tid0-spins the flag, barrier, then ag_loads the data.
// ---------------------------------------------------------------------------
__device__ __forceinline__ void ag_store(float* p, float v) {
    __hip_atomic_store(p, v, __ATOMIC_RELAXED, __HIP_MEMORY_SCOPE_AGENT);
}
__device__ __forceinline__ float ag_load(const float* p) {
    return __hip_atomic_load(p, __ATOMIC_RELAXED, __HIP_MEMORY_SCOPE_AGENT);
}

// fast tanh for attention scores (error ~1e-7, stable at +-inf)
__device__ __forceinline__ float ftanh(float x)
{
    float e = __expf(2.0f * x);
    return 1.0f - 2.0f * __builtin_amdgcn_rcpf(e + 1.0f);
}

// ---------------------------------------------------------------------------
// XU = x @ Uw + Ub.  64x64 tile, BK=32, 256 threads, 4x4 acc/thread.
// ---------------------------------------------------------------------------
__global__ __launch_bounds__(256) void gemm_xu(
    const float* __restrict__ A, const float* __restrict__ W,
    const float* __restrict__ bias, float* __restrict__ C)
{
    __shared__ float At[32][68];   // A tile transposed: At[k][m]
    __shared__ float Ws[32][68];
    const int tid = threadIdx.x;
    const int n0 = blockIdx.x * 64;
    const int m0 = blockIdx.y * 64;
    const int tx = tid & 15, ty = tid >> 4;
    const int arow = tid >> 3, ak = (tid & 7) << 2;
    const int wrow = tid >> 4, wc = (tid & 15) << 2;

    float acc[4][4] = {};

    for (int k0 = 0; k0 < kINP; k0 += 32) {
        float4 a0 = *reinterpret_cast<const float4*>(&A[(size_t)(m0 + arow) * kINP + k0 + ak]);
        float4 a1 = *reinterpret_cast<const float4*>(&A[(size_t)(m0 + 32 + arow) * kINP + k0 + ak]);
        float4 w0 = *reinterpret_cast<const float4*>(&W[(size_t)(k0 + wrow) * kH + n0 + wc]);
        float4 w1 = *reinterpret_cast<const float4*>(&W[(size_t)(k0 + wrow + 16) * kH + n0 + wc]);
        __syncthreads();
        At[ak + 0][arow] = a0.x; At[ak + 1][arow] = a0.y;
        At[ak + 2][arow] = a0.z; At[ak + 3][arow] = a0.w;
        At[ak + 0][32 + arow] = a1.x; At[ak + 1][32 + arow] = a1.y;
        At[ak + 2][32 + arow] = a1.z; At[ak + 3][32 + arow] = a1.w;
        *reinterpret_cast<float4*>(&Ws[wrow][wc]) = w0;
        *reinterpret_cast<float4*>(&Ws[wrow + 16][wc]) = w1;
        __syncthreads();
#pragma unroll
        for (int kk = 0; kk < 32; ++kk) {
            float4 a4 = *reinterpret_cast<float4*>(&At[kk][ty * 4]);
            float4 w4 = *reinterpret_cast<float4*>(&Ws[kk][tx * 4]);
            float a_[4] = {a4.x, a4.y, a4.z, a4.w};
            float w_[4] = {w4.x, w4.y, w4.z, w4.w};
#pragma unroll
            for (int r = 0; r < 4; ++r)
#pragma unroll
                for (int c = 0; c < 4; ++c)
                    acc[r][c] += a_[r] * w_[c];
        }
    }

#pragma unroll
    for (int r = 0; r < 4; ++r) {
        int m = m0 + ty * 4 + r;
#pragma unroll
        for (int c = 0; c < 4; ++c) {
            int n = n0 + tx * 4 + c;
            C[(size_t)m * kH + n] = acc[r][c] + bias[n];
        }
    }
}

__global__ __launch_bounds__(256) void init_flags_k(int* __restrict__ flags)
{
    int i = blockIdx.x * 256 + threadIdx.x;
    if (i < kB * 3 * 2) flags[i] = 0;
}

// ---------------------------------------------------------------------------
// Pair-split persistent recurrence (r5 structure): blockIdx = 2*b + half,
// 1024 threads. Each block owns n-cols [C0,C0+256). On-chip caches of own
// column half: shortH/shortU (last-32 h/u) + longH (64 long-term h rows) in
// LDS; lngU block-private global (L2-resident). Weight matvecs split own-k /
// partner-k around the pair flag waits. Per-wave register softmax.
// XU is streamed with non-temporal loads to avoid evicting weights from L2.
// ---------------------------------------------------------------------------
__global__ __launch_bounds__(1024) void rnn_pair(
    const float* __restrict__ Vw, const float* __restrict__ Vaw,
    const float* __restrict__ Uaw, const float* __restrict__ vvec,
    const float* __restrict__ XU, float* __restrict__ lngU,
    float* __restrict__ hs, float* __restrict__ esx,
    float* __restrict__ stx, int* __restrict__ flags)
{
    extern __shared__ float dyn[];
    float* shortH = dyn;               // [32][256]
    float* shortU = dyn + 32 * 256;    // [32][256]
    float* longH  = dyn + 64 * 256;    // [64][256]
    float* part   = dyn + 128 * 256;   // [16][260]
    const int PSTR = 260;

    const int bid = blockIdx.x;
    const int b = bid >> 1, half = bid & 1;
    const int C0 = half << 8;            // own column base
    const int P0 = (half ^ 1) << 8;      // partner column base
    const int tid = threadIdx.x;
    const int kq = tid >> 6;             // wave id 0..15 (k-split group)
    const int lane = tid & 63;
    const int c4 = lane << 2;            // float4 col offset within half

    __shared__ __align__(16) float h_sh[512];     // full h_{t-1}
    __shared__ __align__(16) float st_sh[512];    // full st
    __shared__ __align__(16) float va_sh[256];    // own cols of va
    __shared__ __align__(16) float v_sh[256];     // own cols of v
    __shared__ float es_own[96], es_sh[96];
    __shared__ int   rowm[96];
    __shared__ float lsc_sh[kT];
    __shared__ float buck_sh[kR];
    __shared__ int   lidx_sh[kR];
    __shared__ int   fcnt_sh, evict_pos;

    float* lngU_b = lngU + (size_t)bid * kR * 256;

    int* fC_own = &flags[(b * 3 + 0) * 2 + half];
    int* fB_own = &flags[(b * 3 + 1) * 2 + half];
    int* fS_own = &flags[(b * 3 + 2) * 2 + half];
    int* fC_par = &flags[(b * 3 + 0) * 2 + (half ^ 1)];
    int* fB_par = &flags[(b * 3 + 1) * 2 + (half ^ 1)];
    int* fS_par = &flags[(b * 3 + 2) * 2 + (half ^ 1)];

    auto wait_ge = [&](int* f, int target) {
        if (tid == 0) {
            while (__hip_atomic_load(f, __ATOMIC_RELAXED, __HIP_MEMORY_SCOPE_AGENT) < target)
                __builtin_amdgcn_s_sleep(1);
        }
        __syncthreads();
    };
    auto set_flag = [&](int* f, int val) {
        __syncthreads();   // drains vmcnt(0): prior agent stores at coherence point
        if (tid == 0)
            __hip_atomic_store(f, val, __ATOMIC_RELAXED, __HIP_MEMORY_SCOPE_AGENT);
    };

    // ---- prologue (t = 0): st_0 = pre = XU[0][b];  h_0 = tanh(pre)
    if (tid < 256) { v_sh[tid] = vvec[C0 + tid]; lsc_sh[tid] = 0.0f; }
    if (tid < kR) { buck_sh[tid] = 0.0f; lidx_sh[tid] = -1; }
    if (tid == 0) fcnt_sh = 0;
    if (tid < 512) st_sh[tid] = __builtin_nontemporal_load(&XU[(size_t)b * kH + tid]);
    __syncthreads();
    if (tid < 256) {
        float h0 = tanhf(st_sh[C0 + tid]);
        h_sh[C0 + tid] = h0;
        shortH[tid] = h0;                       // slot 0 <- h_0
        ag_store(&hs[(size_t)b * kH + C0 + tid], h0);
    }
    set_flag(fC_own, 1);
    // va_0 = st_0 @ Vaw[:, C]  (full k: st_0 known from XU, no partner needed)
    {
        float4 acc = {0, 0, 0, 0};
#pragma unroll 8
        for (int k = kq; k < kH; k += 16) {
            float s = st_sh[k];
            const float4 w = *reinterpret_cast<const float4*>(&Vaw[(size_t)k * kH + C0 + c4]);
            acc.x += s * w.x; acc.y += s * w.y; acc.z += s * w.z; acc.w += s * w.w;
        }
        *reinterpret_cast<float4*>(&part[kq * PSTR + c4]) = acc;
        __syncthreads();
        if (tid < 256) {
            float s = 0.0f;
#pragma unroll
            for (int j = 0; j < 16; ++j) s += part[j * PSTR + tid];
            va_sh[tid] = s;
        }
        __syncthreads();
    }

    for (int t = 1; t < kT; ++t) {
        // XU[t] prefetch for the matvec-B epilogue (non-temporal: read-once)
        float xu_reg = 0.0f;
        if (tid < 256)
            xu_reg = __builtin_nontemporal_load(&XU[((size_t)t * kB + b) * kH + C0 + tid]);

        // ---- matvec A phase 1 (own-k): u = h_{t-1} @ Uaw[:, C]
        float4 accA = {0, 0, 0, 0};
#pragma unroll 8
        for (int k = C0 + kq; k < C0 + 256; k += 16) {
            float s = h_sh[k];
            const float4 w = *reinterpret_cast<const float4*>(&Uaw[(size_t)k * kH + C0 + c4]);
            accA.x += s * w.x; accA.y += s * w.y; accA.z += s * w.z; accA.w += s * w.w;
        }
        if (tid < 96) {
            int row;
            if (tid < kK) { int md = (t + 31 - tid) & 31; row = t - 1 - md; }
            else row = lidx_sh[tid - kK];     // >=0 means slot filled
            rowm[tid] = row;
        }
        wait_ge(fC_par, t);
        if (tid < 256) h_sh[P0 + tid] = ag_load(&hs[((size_t)(t - 1) * kB + b) * kH + P0 + tid]);
        __syncthreads();
        // ---- matvec A phase 2 (partner-k)
#pragma unroll 8
        for (int k = P0 + kq; k < P0 + 256; k += 16) {
            float s = h_sh[k];
            const float4 w = *reinterpret_cast<const float4*>(&Uaw[(size_t)k * kH + C0 + c4]);
            accA.x += s * w.x; accA.y += s * w.y; accA.z += s * w.z; accA.w += s * w.w;
        }
        *reinterpret_cast<float4*>(&part[kq * PSTR + c4]) = accA;
        __syncthreads();
        if (tid < 256) {
            float u = 0.0f;
#pragma unroll
            for (int j = 0; j < 16; ++j) u += part[j * PSTR + tid];
            shortU[((t - 1) & 31) * 256 + tid] = u;     // slot (t-1)%32
        }
        __syncthreads();

        // ---- es partials over own cols: wave kq handles rows m = kq + 16r
        {
            float4 uu[6];
            int rv[6];
#pragma unroll
            for (int r = 0; r < 6; ++r) {
                int m = kq + (r << 4);
                int row = rowm[m];
                rv[r] = row;
                uu[r] = make_float4(0.f, 0.f, 0.f, 0.f);
                if (row >= 0) {
                    const float* up = (m < kK) ? &shortU[m * 256]
                                               : &lngU_b[(size_t)(m - kK) * 256];
                    uu[r] = *reinterpret_cast<const float4*>(&up[c4]);
                }
            }
            const float4 vav = *reinterpret_cast<const float4*>(&va_sh[c4]);
            const float4 vvv = *reinterpret_cast<const float4*>(&v_sh[c4]);
#pragma unroll
            for (int r = 0; r < 6; ++r) {
                float p = 0.0f;
                if (rv[r] >= 0) {
                    p = vvv.x * ftanh(vav.x + uu[r].x) + vvv.y * ftanh(vav.y + uu[r].y)
                      + vvv.z * ftanh(vav.z + uu[r].z) + vvv.w * ftanh(vav.w + uu[r].w);
                }
#pragma unroll
                for (int off = 32; off; off >>= 1) p += __shfl_down(p, off);
                if (lane == 0) es_own[kq + (r << 4)] = p;
            }
        }
        __syncthreads();
        if (tid < 96) ag_store(&esx[((size_t)b * 2 + half) * 96 + tid], es_own[tid]);
        set_flag(fB_own, t);
        wait_ge(fB_par, t);
        if (tid < 96) {
            float e = kNEG;
            if (rowm[tid] >= 0)
                e = es_own[tid] + ag_load(&esx[((size_t)b * 2 + (half ^ 1)) * 96 + tid]);
            es_sh[tid] = e;
        }
        __syncthreads();

        // ---- per-wave register softmax over 96 (redundant, no barriers)
        float mx, inv;
        {
            float a = es_sh[lane];
            float b2 = (lane < 32) ? es_sh[64 + lane] : kNEG;
            float m2 = fmaxf(a, b2);
#pragma unroll
            for (int off = 32; off; off >>= 1) m2 = fmaxf(m2, __shfl_xor(m2, off));
            mx = m2;
            float e = __expf(a - mx) + ((lane < 32) ? __expf(b2 - mx) : 0.0f);
#pragma unroll
            for (int off = 32; off; off >>= 1) e += __shfl_xor(e, off);
            inv = 1.0f / e;
        }

        // ---- ct partials over own cols (shortH / longH, both LDS)
        {
            float4 acc = {0, 0, 0, 0};
#pragma unroll
            for (int r = 0; r < 6; ++r) {
                int m = kq + (r << 4);
                int row = rowm[m];
                if (row >= 0) {
                    const float* hp = (m < kK) ? &shortH[m * 256]
                                               : &longH[(m - kK) * 256];
                    const float4 hv = *reinterpret_cast<const float4*>(&hp[c4]);
                    float wq = __expf(es_sh[m] - mx);
                    acc.x += wq * hv.x; acc.y += wq * hv.y;
                    acc.z += wq * hv.z; acc.w += wq * hv.w;
                }
            }
            *reinterpret_cast<float4*>(&part[kq * PSTR + c4]) = acc;
        }
        __syncthreads();
        if (tid < 256) {
            float ct = 0.0f;
#pragma unroll
            for (int j = 0; j < 16; ++j) ct += part[j * PSTR + tid];
            float stv = 0.5f * (h_sh[C0 + tid] + ct * inv);
            st_sh[C0 + tid] = stv;
            ag_store(&stx[(size_t)b * kH + C0 + tid], stv);
        }
        set_flag(fS_own, t);

        // ---- long_scores accumulate + eviction decision (wave 0 only;
        //      same-wave LDS ordering, no barrier needed inside)
        if (tid < kK) {
            int row = rowm[tid];
            if (row >= 0) lsc_sh[row] += __expf(es_sh[tid] - mx) * inv;
        }
        if (tid == 0) {
            int ep = -1;
            if (t >= kK) {
                float score = lsc_sh[t - kK];
                int fc = fcnt_sh;
                bool nf = fc < kR;
                float mn = buck_sh[0]; int mp = 0;
                for (int r = 1; r < kR; ++r) {
                    float bv = buck_sh[r];
                    if (bv < mn) { mn = bv; mp = r; }
                }
                if (nf || score > mn) {
                    ep = nf ? fc : mp;
                    lidx_sh[ep] = t - kK;
                    buck_sh[ep] = score;
                    if (nf) fcnt_sh = fc + 1;
                }
            }
            evict_pos = ep;
        }
        __syncthreads();
        // evicted candidate = h_{t-32} / u_{t-32} in slot t%32 (copy before
        // the slot is overwritten with h_t below)
        if (evict_pos >= 0 && tid < 256) {
            longH[evict_pos * 256 + tid] = shortH[(t & 31) * 256 + tid];
            lngU_b[(size_t)evict_pos * 256 + tid] = shortU[(t & 31) * 256 + tid];
        }

        // ---- matvec B: h_pre = st @ Vw[:, C] + XU[t]  (own-k, then partner)
        float4 aw4 = {0, 0, 0, 0};
#pragma unroll 8
        for (int k = C0 + kq; k < C0 + 256; k += 16) {
            float s = st_sh[k];
            const float4 w = *reinterpret_cast<const float4*>(&Vw[(size_t)k * kH + C0 + c4]);
            aw4.x += s * w.x; aw4.y += s * w.y; aw4.z += s * w.z; aw4.w += s * w.w;
        }
        wait_ge(fS_par, t);
        if (tid < 256) st_sh[P0 + tid] = ag_load(&stx[(size_t)b * kH + P0 + tid]);
        __syncthreads();
#pragma unroll 8
        for (int k = P0 + kq; k < P0 + 256; k += 16) {
            float s = st_sh[k];
            const float4 w = *reinterpret_cast<const float4*>(&Vw[(size_t)k * kH + C0 + c4]);
            aw4.x += s * w.x; aw4.y += s * w.y; aw4.z += s * w.z; aw4.w += s * w.w;
        }
        *reinterpret_cast<float4*>(&part[kq * PSTR + c4]) = aw4;
        __syncthreads();
        if (tid < 256) {
            float hpre = xu_reg;
#pragma unroll
            for (int j = 0; j < 16; ++j) hpre += part[j * PSTR + tid];
            float hval = tanhf(hpre);
            h_sh[C0 + tid] = hval;
            shortH[(t & 31) * 256 + tid] = hval;       // slot t%32 <- h_t
            ag_store(&hs[((size_t)t * kB + b) * kH + C0 + tid], hval);
        }
        set_flag(fC_own, t + 1);   // unblock partner's next matvec-A early

        // ---- matvec B pass 2 (Vaw): va'[C] = st @ Vaw[:, C]  (full k)
        {
            float4 av = {0, 0, 0, 0};
#pragma unroll 8
            for (int k = kq; k < kH; k += 16) {
                float s = st_sh[k];
                const float4 w = *reinterpret_cast<const float4*>(&Vaw[(size_t)k * kH + C0 + c4]);
                av.x += s * w.x; av.y += s * w.y; av.z += s * w.z; av.w += s * w.w;
            }
            *reinterpret_cast<float4*>(&part[kq * PSTR + c4]) = av;
        }
        __syncthreads();
        if (tid < 256) {
            float vn = 0.0f;
#pragma unroll
            for (int j = 0; j < 16; ++j) vn += part[j * PSTR + tid];
            va_sh[tid] = vn;
        }
        __syncthreads();
    }
}

// ---------------------------------------------------------------------------
extern "C" void kernel_launch(void* const* d_in, const int* in_sizes, int n_in,
                              void* d_out, int out_size, void* d_ws, size_t ws_size,
                              hipStream_t stream)
{
    const float* x   = (const float*)d_in[0];
    const float* Uw  = (const float*)d_in[1];
    const float* Ub  = (const float*)d_in[2];
    const float* Vw  = (const float*)d_in[3];
    const float* Uaw = (const float*)d_in[4];
    const float* Vaw = (const float*)d_in[5];
    const float* vv  = (const float*)d_in[6];
    float* hs = (float*)d_out;

    float* ws = (float*)d_ws;
    const size_t TBH = (size_t)kT * kB * kH;
    float* XU   = ws;                            // T*B*H
    float* lngU = XU + TBH;                      // 2*B * 64 * 256
    float* esx  = lngU + (size_t)2 * kB * kR * 256;
    float* stx  = esx + (size_t)kB * 2 * 96;     // B*H
    int*   flags = (int*)(stx + (size_t)kB * kH);  // B*3*2

    // dynamic LDS: shortH(32K) + shortU(32K) + longH(64K) + part(16.6K)
    const int dyn_bytes = (32 * 256 + 32 * 256 + 64 * 256 + 16 * 260) * 4;
    hipFuncSetAttribute(reinterpret_cast<const void*>(rnn_pair),
                        hipFuncAttributeMaxDynamicSharedMemorySize, dyn_bytes);

    init_flags_k<<<3, 256, 0, stream>>>(flags);

    // XU = x @ Uw + Ub
    gemm_xu<<<dim3(kH / 64, (kT * kB) / 64), 256, 0, stream>>>(x, Uw, Ub, XU);

    // pair-split recurrence: 2 blocks per batch element, 1024 threads each
    rnn_pair<<<2 * kB, 1024, dyn_bytes, stream>>>(
        Vw, Vaw, Uaw, vv, XU, lngU, hs, esx, stx, flags);
}

// Round 10
// 5658.084 us; speedup vs baseline: 2.0340x; 1.1827x over previous
//
#include <hip/hip_runtime.h>
#include <hip/hip_bf16.h>
#include <cstddef>

#define kT 256
#define kB 128
#define kINP 512
#define kH 512
#define kK 32
#define kR 64
#define kNEG (-1e30f)

// ---------------------------------------------------------------------------
// agent-scope (device-coherent, L1/L2-bypassing) accessors, RELAXED order.
// Ordering between the pair blocks: set_flag's __syncthreads drains vmcnt(0)
// per wave before tid0 stores the flag; the partner tid0-spins the flag,
// barriers, then ag_loads the data. Protocol validated r3-r5/r9.
// ---------------------------------------------------------------------------
__device__ __forceinline__ void ag_store(float* p, float v) {
    __hip_atomic_store(p, v, __ATOMIC_RELAXED, __HIP_MEMORY_SCOPE_AGENT);
}
__device__ __forceinline__ float ag_load(const float* p) {
    return __hip_atomic_load(p, __ATOMIC_RELAXED, __HIP_MEMORY_SCOPE_AGENT);
}

// fast tanh for attention scores (error ~1e-7, stable at +-inf)
__device__ __forceinline__ float ftanh(float x)
{
    float e = __expf(2.0f * x);
    return 1.0f - 2.0f * __builtin_amdgcn_rcpf(e + 1.0f);
}

// ---------------------------------------------------------------------------
// XU = x @ Uw + Ub.  64x64 tile, BK=32, 256 threads, 4x4 acc/thread.
// (prelude-only change vs r5; this kernel version passed in r6/r7/r9)
// ---------------------------------------------------------------------------
__global__ __launch_bounds__(256) void gemm_xu(
    const float* __restrict__ A, const float* __restrict__ W,
    const float* __restrict__ bias, float* __restrict__ C)
{
    __shared__ float At[32][68];   // A tile transposed: At[k][m]
    __shared__ float Ws[32][68];
    const int tid = threadIdx.x;
    const int n0 = blockIdx.x * 64;
    const int m0 = blockIdx.y * 64;
    const int tx = tid & 15, ty = tid >> 4;
    const int arow = tid >> 3, ak = (tid & 7) << 2;
    const int wrow = tid >> 4, wc = (tid & 15) << 2;

    float acc[4][4] = {};

    for (int k0 = 0; k0 < kINP; k0 += 32) {
        float4 a0 = *reinterpret_cast<const float4*>(&A[(size_t)(m0 + arow) * kINP + k0 + ak]);
        float4 a1 = *reinterpret_cast<const float4*>(&A[(size_t)(m0 + 32 + arow) * kINP + k0 + ak]);
        float4 w0 = *reinterpret_cast<const float4*>(&W[(size_t)(k0 + wrow) * kH + n0 + wc]);
        float4 w1 = *reinterpret_cast<const float4*>(&W[(size_t)(k0 + wrow + 16) * kH + n0 + wc]);
        __syncthreads();
        At[ak + 0][arow] = a0.x; At[ak + 1][arow] = a0.y;
        At[ak + 2][arow] = a0.z; At[ak + 3][arow] = a0.w;
        At[ak + 0][32 + arow] = a1.x; At[ak + 1][32 + arow] = a1.y;
        At[ak + 2][32 + arow] = a1.z; At[ak + 3][32 + arow] = a1.w;
        *reinterpret_cast<float4*>(&Ws[wrow][wc]) = w0;
        *reinterpret_cast<float4*>(&Ws[wrow + 16][wc]) = w1;
        __syncthreads();
#pragma unroll
        for (int kk = 0; kk < 32; ++kk) {
            float4 a4 = *reinterpret_cast<float4*>(&At[kk][ty * 4]);
            float4 w4 = *reinterpret_cast<float4*>(&Ws[kk][tx * 4]);
            float a_[4] = {a4.x, a4.y, a4.z, a4.w};
            float w_[4] = {w4.x, w4.y, w4.z, w4.w};
#pragma unroll
            for (int r = 0; r < 4; ++r)
#pragma unroll
                for (int c = 0; c < 4; ++c)
                    acc[r][c] += a_[r] * w_[c];
        }
    }

#pragma unroll
    for (int r = 0; r < 4; ++r) {
        int m = m0 + ty * 4 + r;
#pragma unroll
        for (int c = 0; c < 4; ++c) {
            int n = n0 + tx * 4 + c;
            C[(size_t)m * kH + n] = acc[r][c] + bias[n];
        }
    }
}

__global__ __launch_bounds__(256) void init_flags_k(int* __restrict__ flags)
{
    int i = blockIdx.x * 256 + threadIdx.x;
    if (i < kB * 3 * 2) flags[i] = 0;
}

// ---------------------------------------------------------------------------
// Pair-split persistent recurrence — BYTE-IDENTICAL to the round-5 kernel
// (the proven 5,630 us baseline). blockIdx = 2*b + half, 1024 threads.
// On-chip caches of the block's own 256-col half: shortH/shortU (last-32
// h/u rows) + longH (64 long-term h rows) in LDS; lngU block-private global
// (L2-resident). Weight matvecs split own-k / partner-k around pair waits.
// ---------------------------------------------------------------------------
__global__ __launch_bounds__(1024) void rnn_pair(
    const float* __restrict__ Vw, const float* __restrict__ Vaw,
    const float* __restrict__ Uaw, const float* __restrict__ vvec,
    const float* __restrict__ XU, float* __restrict__ lngU,
    float* __restrict__ hs, float* __restrict__ esx,
    float* __restrict__ stx, int* __restrict__ flags)
{
    extern __shared__ float dyn[];
    float* shortH = dyn;               // [32][256]
    float* shortU = dyn + 32 * 256;    // [32][256]
    float* longH  = dyn + 64 * 256;    // [64][256]
    float* part   = dyn + 128 * 256;   // [16][264]
    const int PSTR = 264;

    const int bid = blockIdx.x;
    const int b = bid >> 1, half = bid & 1;
    const int C0 = half << 8;            // own column base
    const int P0 = (half ^ 1) << 8;      // partner column base
    const int tid = threadIdx.x;
    const int kq = tid >> 6;             // 0..15 (wave id / k-split group)
    const int lane = tid & 63;
    const int c4 = lane << 2;            // float4 col offset within half

    __shared__ __align__(16) float h_sh[512];     // full h_{t-1}
    __shared__ __align__(16) float st_sh[512];    // full st
    __shared__ __align__(16) float va_sh[256];    // own cols of va
    __shared__ __align__(16) float v_sh[256];     // own cols of v
    __shared__ float es_own[96], es_sh[96], w_sh[96];
    __shared__ int   rowm[96];
    __shared__ float lsc_sh[kT];
    __shared__ float buck_sh[kR];
    __shared__ int   lidx_sh[kR];
    __shared__ int   fcnt_sh, evict_pos;
    __shared__ float red0, red1;

    float* lngU_b = lngU + (size_t)bid * kR * 256;

    int* fC_own = &flags[(b * 3 + 0) * 2 + half];
    int* fB_own = &flags[(b * 3 + 1) * 2 + half];
    int* fS_own = &flags[(b * 3 + 2) * 2 + half];
    int* fC_par = &flags[(b * 3 + 0) * 2 + (half ^ 1)];
    int* fB_par = &flags[(b * 3 + 1) * 2 + (half ^ 1)];
    int* fS_par = &flags[(b * 3 + 2) * 2 + (half ^ 1)];

    auto wait_ge = [&](int* f, int target) {
        if (tid == 0) {
            while (__hip_atomic_load(f, __ATOMIC_RELAXED, __HIP_MEMORY_SCOPE_AGENT) < target)
                __builtin_amdgcn_s_sleep(1);
        }
        __syncthreads();
    };
    auto set_flag = [&](int* f, int val) {
        __syncthreads();   // drains vmcnt(0): prior agent stores at coherence point
        if (tid == 0)
            __hip_atomic_store(f, val, __ATOMIC_RELAXED, __HIP_MEMORY_SCOPE_AGENT);
    };

    // ---- prologue (t = 0)
    if (tid < 256) { v_sh[tid] = vvec[C0 + tid]; lsc_sh[tid] = 0.0f; }
    if (tid < kR) { buck_sh[tid] = 0.0f; lidx_sh[tid] = -1; }
    if (tid == 0) fcnt_sh = 0;
    if (tid < 512) st_sh[tid] = XU[(size_t)b * kH + tid];   // st_0 = pre
    __syncthreads();
    if (tid < 256) {
        float h0 = tanhf(st_sh[C0 + tid]);
        h_sh[C0 + tid] = h0;
        shortH[tid] = h0;                       // slot 0 <- h_0
        ag_store(&hs[(size_t)b * kH + C0 + tid], h0);
    }
    set_flag(fC_own, 1);
    // va_0 = st_0 @ Vaw[:, C]  (full k: st_0 known from XU, no partner needed)
    {
        float4 acc = {0, 0, 0, 0};
#pragma unroll 8
        for (int k = kq; k < kH; k += 16) {
            float s = st_sh[k];
            const float4 w = *reinterpret_cast<const float4*>(&Vaw[(size_t)k * kH + C0 + c4]);
            acc.x += s * w.x; acc.y += s * w.y; acc.z += s * w.z; acc.w += s * w.w;
        }
        *reinterpret_cast<float4*>(&part[kq * PSTR + c4]) = acc;
        __syncthreads();
        if (tid < 256) {
            float s = 0.0f;
#pragma unroll
            for (int j = 0; j < 16; ++j) s += part[j * PSTR + tid];
            va_sh[tid] = s;
        }
        __syncthreads();
    }

    for (int t = 1; t < kT; ++t) {
        // XU[t] prefetch for the matvec-B epilogue
        float xu_reg = 0.0f;
        if (tid < 256) xu_reg = XU[((size_t)t * kB + b) * kH + C0 + tid];

        // ---- matvec A phase 1 (own-k): u = h_{t-1} @ Uaw[:, C]
        float4 accA = {0, 0, 0, 0};
#pragma unroll 8
        for (int k = C0 + kq; k < C0 + 256; k += 16) {
            float s = h_sh[k];
            const float4 w = *reinterpret_cast<const float4*>(&Uaw[(size_t)k * kH + C0 + c4]);
            accA.x += s * w.x; accA.y += s * w.y; accA.z += s * w.z; accA.w += s * w.w;
        }
        if (tid < 96) {
            int row;
            if (tid < kK) { int md = (t + 31 - tid) & 31; row = t - 1 - md; }
            else row = lidx_sh[tid - kK];     // >=0 means slot filled
            rowm[tid] = row;
        }
        wait_ge(fC_par, t);
        if (tid < 256) h_sh[P0 + tid] = ag_load(&hs[((size_t)(t - 1) * kB + b) * kH + P0 + tid]);
        __syncthreads();
        // ---- matvec A phase 2 (partner-k)
#pragma unroll 8
        for (int k = P0 + kq; k < P0 + 256; k += 16) {
            float s = h_sh[k];
            const float4 w = *reinterpret_cast<const float4*>(&Uaw[(size_t)k * kH + C0 + c4]);
            accA.x += s * w.x; accA.y += s * w.y; accA.z += s * w.z; accA.w += s * w.w;
        }
        *reinterpret_cast<float4*>(&part[kq * PSTR + c4]) = accA;
        __syncthreads();
        if (tid < 256) {
            float u = 0.0f;
#pragma unroll
            for (int j = 0; j < 16; ++j) u += part[j * PSTR + tid];
            shortU[((t - 1) & 31) * 256 + tid] = u;     // slot (t-1)%32
        }
        __syncthreads();

        // ---- es partials over own cols: wave kq handles rows m = kq + 16r
        {
            float4 uu[6];
            int rv[6];
#pragma unroll
            for (int r = 0; r < 6; ++r) {
                int m = kq + (r << 4);
                int row = rowm[m];
                rv[r] = row;
                uu[r] = make_float4(0.f, 0.f, 0.f, 0.f);
                if (row >= 0) {
                    const float* up = (m < kK) ? &shortU[m * 256]
                                               : &lngU_b[(size_t)(m - kK) * 256];
                    uu[r] = *reinterpret_cast<const float4*>(&up[c4]);
                }
            }
            const float4 vav = *reinterpret_cast<const float4*>(&va_sh[c4]);
            const float4 vvv = *reinterpret_cast<const float4*>(&v_sh[c4]);
#pragma unroll
            for (int r = 0; r < 6; ++r) {
                float p = 0.0f;
                if (rv[r] >= 0) {
                    p = vvv.x * ftanh(vav.x + uu[r].x) + vvv.y * ftanh(vav.y + uu[r].y)
                      + vvv.z * ftanh(vav.z + uu[r].z) + vvv.w * ftanh(vav.w + uu[r].w);
                }
#pragma unroll
                for (int off = 32; off; off >>= 1) p += __shfl_down(p, off);
                if (lane == 0) es_own[kq + (r << 4)] = p;
            }
        }
        __syncthreads();
        if (tid < 96) ag_store(&esx[((size_t)b * 2 + half) * 96 + tid], es_own[tid]);
        set_flag(fB_own, t);
        wait_ge(fB_par, t);
        if (tid < 96) {
            float e = kNEG;
            if (rowm[tid] >= 0)
                e = es_own[tid] + ag_load(&esx[((size_t)b * 2 + (half ^ 1)) * 96 + tid]);
            es_sh[tid] = e;
        }
        __syncthreads();

        // ---- softmax over 96 (redundant in both halves, bitwise identical)
        if (tid < 64) {
            float a = es_sh[tid];
            float c = (tid < 32) ? es_sh[64 + tid] : kNEG;
            float mx = fmaxf(a, c);
#pragma unroll
            for (int off = 32; off; off >>= 1) mx = fmaxf(mx, __shfl_xor(mx, off));
            if (tid == 0) red0 = mx;
        }
        __syncthreads();
        if (tid < 96) w_sh[tid] = __expf(es_sh[tid] - red0);
        __syncthreads();
        if (tid < 64) {
            float a = w_sh[tid] + ((tid < 32) ? w_sh[64 + tid] : 0.0f);
#pragma unroll
            for (int off = 32; off; off >>= 1) a += __shfl_xor(a, off);
            if (tid == 0) red1 = 1.0f / a;
        }
        __syncthreads();

        // ---- ct partials over own cols (shortH / longH, both LDS)
        {
            float4 hv[6]; float wq[6];
#pragma unroll
            for (int r = 0; r < 6; ++r) {
                int m = kq + (r << 4);
                int row = rowm[m];
                hv[r] = make_float4(0.f, 0.f, 0.f, 0.f); wq[r] = 0.0f;
                if (row >= 0) {
                    const float* hp = (m < kK) ? &shortH[m * 256]
                                               : &longH[(m - kK) * 256];
                    hv[r] = *reinterpret_cast<const float4*>(&hp[c4]);
                    wq[r] = w_sh[m];
                }
            }
            float4 acc = {0, 0, 0, 0};
#pragma unroll
            for (int r = 0; r < 6; ++r) {
                acc.x += wq[r] * hv[r].x; acc.y += wq[r] * hv[r].y;
                acc.z += wq[r] * hv[r].z; acc.w += wq[r] * hv[r].w;
            }
            *reinterpret_cast<float4*>(&part[kq * PSTR + c4]) = acc;
        }
        __syncthreads();
        if (tid < 256) {
            float ct = 0.0f;
#pragma unroll
            for (int j = 0; j < 16; ++j) ct += part[j * PSTR + tid];
            float stv = 0.5f * (h_sh[C0 + tid] + ct * red1);
            st_sh[C0 + tid] = stv;
            ag_store(&stx[(size_t)b * kH + C0 + tid], stv);
        }
        set_flag(fS_own, t);

        // ---- long_scores accumulation, then eviction decision (ref order)
        if (tid < kK) {
            int row = rowm[tid];
            if (row >= 0) lsc_sh[row] += w_sh[tid] * red1;
        }
        __syncthreads();
        if (tid == 0) {
            int ep = -1;
            if (t >= kK) {
                float score = lsc_sh[t - kK];
                int fc = fcnt_sh;
                bool nf = fc < kR;
                float mn = buck_sh[0]; int mp = 0;
                for (int r = 1; r < kR; ++r) {
                    float bv = buck_sh[r];
                    if (bv < mn) { mn = bv; mp = r; }
                }
                if (nf || score > mn) {
                    ep = nf ? fc : mp;
                    lidx_sh[ep] = t - kK;
                    buck_sh[ep] = score;
                    if (nf) fcnt_sh = fc + 1;
                }
            }
            evict_pos = ep;
        }
        __syncthreads();
        // evicted candidate = h_{t-32} = shortH slot t%32 (u likewise) —
        // copy BEFORE the slot is overwritten with h_t at step end.
        if (evict_pos >= 0 && tid < 256) {
            longH[evict_pos * 256 + tid] = shortH[(t & 31) * 256 + tid];
            lngU_b[(size_t)evict_pos * 256 + tid] = shortU[(t & 31) * 256 + tid];
        }

        // ---- matvec B pass 1 (Vw): h_pre[C] = st @ Vw[:, C] + XU[t]
        {
            float4 aw = {0, 0, 0, 0};
#pragma unroll 8
            for (int k = C0 + kq; k < C0 + 256; k += 16) {
                float s = st_sh[k];
                const float4 w = *reinterpret_cast<const float4*>(&Vw[(size_t)k * kH + C0 + c4]);
                aw.x += s * w.x; aw.y += s * w.y; aw.z += s * w.z; aw.w += s * w.w;
            }
            wait_ge(fS_par, t);
            if (tid < 256) st_sh[P0 + tid] = ag_load(&stx[(size_t)b * kH + P0 + tid]);
            __syncthreads();
#pragma unroll 8
            for (int k = P0 + kq; k < P0 + 256; k += 16) {
                float s = st_sh[k];
                const float4 w = *reinterpret_cast<const float4*>(&Vw[(size_t)k * kH + C0 + c4]);
                aw.x += s * w.x; aw.y += s * w.y; aw.z += s * w.z; aw.w += s * w.w;
            }
            *reinterpret_cast<float4*>(&part[kq * PSTR + c4]) = aw;
        }
        __syncthreads();
        if (tid < 256) {
            float hpre = xu_reg;
#pragma unroll
            for (int j = 0; j < 16; ++j) hpre += part[j * PSTR + tid];
            float hv = tanhf(hpre);
            h_sh[C0 + tid] = hv;
            shortH[(t & 31) * 256 + tid] = hv;      // slot t%32 <- h_t
            ag_store(&hs[((size_t)t * kB + b) * kH + C0 + tid], hv);
        }
        set_flag(fC_own, t + 1);   // unblock partner's next matvec-A early

        // ---- matvec B pass 2 (Vaw): va'[C] = st @ Vaw[:, C]  (full k)
        {
            float4 av = {0, 0, 0, 0};
#pragma unroll 8
            for (int k = kq; k < kH; k += 16) {
                float s = st_sh[k];
                const float4 w = *reinterpret_cast<const float4*>(&Vaw[(size_t)k * kH + C0 + c4]);
                av.x += s * w.x; av.y += s * w.y; av.z += s * w.z; av.w += s * w.w;
            }
            *reinterpret_cast<float4*>(&part[kq * PSTR + c4]) = av;
        }
        __syncthreads();
        if (tid < 256) {
            float vn = 0.0f;
#pragma unroll
            for (int j = 0; j < 16; ++j) vn += part[j * PSTR + tid];
            va_sh[tid] = vn;
        }
        __syncthreads();
    }
}

// ---------------------------------------------------------------------------
extern "C" void kernel_launch(void* const* d_in, const int* in_sizes, int n_in,
                              void* d_out, int out_size, void* d_ws, size_t ws_size,
                              hipStream_t stream)
{
    const float* x   = (const float*)d_in[0];
    const float* Uw  = (const float*)d_in[1];
    const float* Ub  = (const float*)d_in[2];
    const float* Vw  = (const float*)d_in[3];
    const float* Uaw = (const float*)d_in[4];
    const float* Vaw = (const float*)d_in[5];
    const float* vv  = (const float*)d_in[6];
    float* hs = (float*)d_out;

    float* ws = (float*)d_ws;
    const size_t TBH = (size_t)kT * kB * kH;
    float* XU   = ws;                            // T*B*H
    float* lngU = XU + TBH;                      // 2*B * 64 * 256
    float* esx  = lngU + (size_t)2 * kB * kR * 256;
    float* stx  = esx + (size_t)kB * 2 * 96;     // B*H
    int*   flags = (int*)(stx + (size_t)kB * kH);  // B*3*2

    // dynamic LDS: shortH(32K) + shortU(32K) + longH(64K) + part(16.5K)
    const int dyn_bytes = (32 * 256 + 32 * 256 + 64 * 256 + 16 * 264) * 4;
    hipFuncSetAttribute(reinterpret_cast<const void*>(rnn_pair),
                        hipFuncAttributeMaxDynamicSharedMemorySize, dyn_bytes);

    init_flags_k<<<3, 256, 0, stream>>>(flags);

    // XU = x @ Uw + Ub
    gemm_xu<<<dim3(kH / 64, (kT * kB) / 64), 256, 0, stream>>>(x, Uw, Ub, XU);

    // pair-split recurrence: 2 blocks per batch element, 1024 threads each
    rnn_pair<<<2 * kB, 1024, dyn_bytes, stream>>>(
        Vw, Vaw, Uaw, vv, XU, lngU, hs, esx, stx, flags);
}